// Round 19
// baseline (226.935 us; speedup 1.0000x reference)
//
#include <hip/hip_runtime.h>

// NONA: out = softmax(-cdist(x, x_n), axis=1) @ y
//   x[4096,1024] f32, x_n[8192,1024] f32, y[8192,128] f32, log_T unused.
//
// R19 = R18 main kernel (verified 4x at 122.0us total / 95.5us main) +
// combine fused into main via deterministic split-K fixup:
//  * each block: write Opart/Lpart slice; __threadfence() (release, makes
//    stores visible device-wide incl. cross-XCD); __syncthreads(); tid0
//    atomicAdd(cnt[rb], agent acq_rel). Block seeing old==SPLIT-1 re-reads
//    all 16 slices IN FIXED s-ORDER (deterministic result regardless of
//    which block runs it), reduces, divides by row denominators, writes out.
//  * cnt[32] zeroed by prep_all block 0 (stream-ordered; inter-kernel
//    coherence). combine kernel + its launch gap eliminated; fixup's 32MB
//    re-read overlaps main's straggler blocks.
//  * main loop / seam / geometry BYTE-IDENTICAL to R18 (no touch).
//
// ws: xb@0 8Mi | xnb@8Mi 16Mi | yT@24Mi 2Mi | xsq@26Mi 16Ki | xnsq +16Ki |
//     Lpart@26Mi+64Ki 256Ki | cnt@26Mi+512Ki 128B | Opart@27Mi 32Mi

#define N_ 4096
#define M_ 8192
#define D_ 1024
#define C_ 128
#define SPLIT 16
#define MCOLS (M_ / SPLIT)    // 512
#define NBN (MCOLS / 128)     // 4
#define NKK (D_ / 64)         // 16

typedef __bf16 bf16;
typedef __attribute__((ext_vector_type(8))) __bf16 bf16x8;
typedef __attribute__((ext_vector_type(4))) __bf16 bf16x4;
typedef __attribute__((ext_vector_type(4))) float f32x4;

__device__ __forceinline__ void async_copy16(const bf16* gp, void* lp) {
  __builtin_amdgcn_global_load_lds(
      (__attribute__((address_space(1))) void*)const_cast<bf16*>(gp),
      (__attribute__((address_space(3))) void*)lp, 16, 0, 0);
}

// 128-B-row tiles (A/B): 16B-granule XOR row&7 (0-conflict, R1-R18)
__device__ __forceinline__ int swz(int row, int gran) {
  return (row << 7) + ((gran ^ (row & 7)) << 4);
}
// 256-B-row tiles (P/V): 16 granules, XOR row&15
__device__ __forceinline__ int swz2(int row, int gran) {
  return (row << 8) + ((gran ^ (row & 15)) << 4);
}

// [128][64]-bf16 tile (16K, 16 chunks): 4 loads/thread @256 thr, src pre-swz
__device__ __forceinline__ void stage16(const bf16* src, char* lds, int tid) {
  const int lane = tid & 63, wave = tid >> 6;
#pragma unroll
  for (int j = 0; j < 4; ++j) {
    const int ch  = j * 4 + wave;
    const int off = ch * 1024 + lane * 16;
    const int row = off >> 7;
    const int gr  = ((off >> 4) & 7) ^ (row & 7);
    async_copy16(src + (size_t)row * D_ + gr * 8, lds + ch * 1024);
  }
}
// V = yT[128 C][128 xn] (32K, 256-B rows): 8 loads/thread @256 thr
__device__ __forceinline__ void stageV(const bf16* yT, int colbase, char* lds, int tid) {
  const int lane = tid & 63, wave = tid >> 6;
#pragma unroll
  for (int j = 0; j < 8; ++j) {
    const int ch  = j * 4 + wave;
    const int off = ch * 1024 + lane * 16;
    const int row = off >> 8;
    const int gr  = ((off >> 4) & 15) ^ (row & 15);
    async_copy16(yT + (size_t)row * M_ + colbase + gr * 8, lds + ch * 1024);
  }
}

#define VM0 asm volatile("s_waitcnt vmcnt(0)" ::: "memory")

__global__ __launch_bounds__(256, 2)   // 2 waves/EU => 2 blocks/CU
void nona_main(const bf16* __restrict__ xb, const bf16* __restrict__ xnb,
               const bf16* __restrict__ yT, const float* __restrict__ xsq,
               const float* __restrict__ xnsq, float* __restrict__ Opart,
               float* __restrict__ Lpart, int* __restrict__ cnt,
               float* __restrict__ out)
{
  __shared__ __align__(16) char Lds[65536];
  char* const A0 = Lds;             // x [128][64] even kk  | seam: P [128][128]
  char* const A1 = Lds + 16384;     // x [128][64] odd kk
  char* const B0 = Lds + 32768;     // xn [128][64] even kk | seam: V [128C][128]
  char* const B1 = Lds + 49152;     // xn [128][64] odd kk
  char* const Pb = A0;              // P, 256-B rows (swz2)
  char* const Vb = B0;              // V, 256-B rows (swz2)

  const int tid  = threadIdx.x;
  const int lane = tid & 63;
  const int wave = tid >> 6;           // 4 waves: wr = wave>>1 (64 rows), wc = wave&1
  const int wr = wave >> 1, wc = wave & 1;
  const int g = lane >> 4, c = lane & 15;

  // 2D XCD-chunked decode: xcd = bid&7 owns 16 rb x 4 s
  const int xcd = blockIdx.x & 7;
  const int idx = blockIdx.x >> 3;               // 0..63
  const int rb  = ((xcd >> 2) << 4) | (idx >> 2);   // 0..31
  const int s   = ((xcd & 3) << 2) | (idx & 3);     // 0..15
  const int row0 = rb * 128;
  const int col0 = s * MCOLS;

  const bf16* xA = xb + (size_t)row0 * D_;

  float xs[4];
#pragma unroll
  for (int rf = 0; rf < 4; ++rf)
    xs[rf] = xsq[row0 + wr * 64 + rf * 16 + c];

  f32x4 Oacc[4][4];
  const f32x4 zero = {0.f, 0.f, 0.f, 0.f};
#pragma unroll
  for (int rf = 0; rf < 4; ++rf)
#pragma unroll
    for (int cc = 0; cc < 4; ++cc) Oacc[rf][cc] = zero;
  float lsum[4] = {0.f, 0.f, 0.f, 0.f};

#pragma unroll 1
  for (int bn = 0; bn < NBN; ++bn) {
    const int colbase = col0 + bn * 128;
    const bf16* xB = xnb + (size_t)colbase * D_;

    f32x4 Sacc[4][4];
#pragma unroll
    for (int rf = 0; rf < 4; ++rf)
#pragma unroll
      for (int cf = 0; cf < 4; ++cf) Sacc[rf][cf] = zero;

    // prologue (prev bn sealed by post-PV syncthreads; vm=0): stage(0)
    stage16(xA, A0, tid);
    stage16(xB, B0, tid);

#pragma unroll 1
    for (int kk = 0; kk < NKK; ++kk) {
      VM0;                           // own stage(kk) landed (only outstanding
                                     // VMEM: stage(kk+1) not yet issued)
      __builtin_amdgcn_s_barrier();  // bar1: all waves' stage(kk) landed;
                                     // also: all waves consumed reads(kk-1)
                                     // before arriving -> WAR-safe restage
      __builtin_amdgcn_sched_barrier(0);
      const char* Ac = (kk & 1) ? A1 : A0;
      const char* Bc = (kk & 1) ? B1 : B0;
      // swapped-S: Sacc = mfma(A=xn_frag, B=x_frag) -> lane holds
      // S[xn = wc*64+cf*16+g*4+r][xrow = wr*64+rf*16+c]
      {
        bf16x8 af[4], bv[4];
#pragma unroll
        for (int rf = 0; rf < 4; ++rf)
          af[rf] = *(const bf16x8*)(Ac + swz(wr * 64 + rf * 16 + c, g));
#pragma unroll
        for (int j = 0; j < 4; ++j)
          bv[j] = *(const bf16x8*)(Bc + swz(wc * 64 + j * 16 + c, g));
        if (kk < NKK - 1) {          // stage(kk+1): AFTER bar1 -> WAR-safe
          stage16(xA + (kk + 1) * 64, (kk & 1) ? A0 : A1, tid);
          stage16(xB + (kk + 1) * 64, (kk & 1) ? B0 : B1, tid);
        }
        __builtin_amdgcn_s_setprio(1);
#pragma unroll
        for (int j = 0; j < 4; ++j)
#pragma unroll
          for (int rf = 0; rf < 4; ++rf)
            Sacc[rf][j] = __builtin_amdgcn_mfma_f32_16x16x32_bf16(
                bv[j], af[rf], Sacc[rf][j], 0, 0, 0);
        __builtin_amdgcn_s_setprio(0);
      }
      {
        bf16x8 af[4], bv[4];
#pragma unroll
        for (int rf = 0; rf < 4; ++rf)
          af[rf] = *(const bf16x8*)(Ac + swz(wr * 64 + rf * 16 + c, 4 + g));
#pragma unroll
        for (int j = 0; j < 4; ++j)
          bv[j] = *(const bf16x8*)(Bc + swz(wc * 64 + j * 16 + c, 4 + g));
        __builtin_amdgcn_s_setprio(1);
#pragma unroll
        for (int j = 0; j < 4; ++j)
#pragma unroll
          for (int rf = 0; rf < 4; ++rf)
            Sacc[rf][j] = __builtin_amdgcn_mfma_f32_16x16x32_bf16(
                bv[j], af[rf], Sacc[rf][j], 0, 0, 0);
        __builtin_amdgcn_s_setprio(0);
      }
      // no bar2: next step's bar1 provides the WAR seal (R14 proof)
    }
    __syncthreads();                 // seal kk15 readers; vm = 0 for alias reuse

    stageV(yT, colbase, Vb, tid);    // V -> B region (flies under exp)

    // exp: w = exp(-sqrt(max(xsq + xnsq - 2*dot, 0))); accumulate l
#pragma unroll
    for (int cf = 0; cf < 4; ++cf) {
      const float4 nsq4 = *(const float4*)(xnsq + colbase + wc * 64 + cf * 16 + g * 4);
#pragma unroll
      for (int rf = 0; rf < 4; ++rf)
#pragma unroll
        for (int r = 0; r < 4; ++r) {
          float d2 = xs[rf] + ((const float*)&nsq4)[r] - 2.0f * Sacc[rf][cf][r];
          d2 = fmaxf(d2, 0.0f);
          const float wv = __expf(-sqrtf(d2));
          lsum[rf] += wv;
          Sacc[rf][cf][r] = wv;
        }
    }

    // P-write -> A region [128 xrow][128 xn] swz2 (b64 per (rf,cf))
#pragma unroll
    for (int rf = 0; rf < 4; ++rf)
#pragma unroll
      for (int cf = 0; cf < 4; ++cf) {
        bf16x4 pk;
#pragma unroll
        for (int r = 0; r < 4; ++r) pk[r] = (bf16)Sacc[rf][cf][r];
        const int prow = wr * 64 + rf * 16 + c;
        const int gran = wc * 8 + cf * 2 + (g >> 1);
        *(bf16x4*)(Pb + (prow << 8) + ((gran ^ (prow & 15)) << 4) + (g & 1) * 8) = pk;
      }
    __syncthreads();                 // drains V (vmcnt0); P visible

    // PV: O[64 rows x 64 C-half] += P[64 x 128] @ V^T  (V [128C][128])
#pragma unroll
    for (int ks = 0; ks < 4; ++ks) {
      bf16x8 pa[4], vb[4];
#pragma unroll
      for (int rf = 0; rf < 4; ++rf)
        pa[rf] = *(const bf16x8*)(Pb + swz2(wr * 64 + rf * 16 + c, ks * 4 + g));
#pragma unroll
      for (int cc = 0; cc < 4; ++cc)
        vb[cc] = *(const bf16x8*)(Vb + swz2(wc * 64 + cc * 16 + c, ks * 4 + g));
      __builtin_amdgcn_s_setprio(1);
#pragma unroll
      for (int cc = 0; cc < 4; ++cc)
#pragma unroll
        for (int rf = 0; rf < 4; ++rf)
          Oacc[rf][cc] = __builtin_amdgcn_mfma_f32_16x16x32_bf16(pa[rf], vb[cc], Oacc[rf][cc], 0, 0, 0);
      __builtin_amdgcn_s_setprio(0);
    }
    __syncthreads();                 // seal P/V readers before next bn prologue
  }

  // ---- L reduce: over g (shfl), then the wc pair (LDS) ----
  float* Lr = (float*)Lds;           // [2 wc][128 rows]
#pragma unroll
  for (int rf = 0; rf < 4; ++rf) {
    float v = lsum[rf];
    v += __shfl_xor(v, 16);
    v += __shfl_xor(v, 32);
    if (g == 0) Lr[wc * 128 + wr * 64 + rf * 16 + c] = v;
  }
  __syncthreads();
  if (tid < 128)
    Lpart[(size_t)s * N_ + row0 + tid] = Lr[tid] + Lr[128 + tid];

  float* ob = Opart + ((size_t)s * N_ + row0) * C_;
#pragma unroll
  for (int rf = 0; rf < 4; ++rf)
#pragma unroll
    for (int cc = 0; cc < 4; ++cc)
#pragma unroll
      for (int r = 0; r < 4; ++r)
        ob[(wr * 64 + rf * 16 + g * 4 + r) * C_ + wc * 64 + cc * 16 + c] = Oacc[rf][cc][r];

  // ---- split-K fixup: last-arriving block for this rb reduces partials ----
  __threadfence();                   // release: Opart/Lpart stores device-visible
  __syncthreads();                   // all threads' stores+fences done; Lr dead
  int* flag = (int*)Lds;
  if (tid == 0)
    flag[0] = (int)__hip_atomic_fetch_add(&cnt[rb], 1, __ATOMIC_ACQ_REL,
                                          __HIP_MEMORY_SCOPE_AGENT);
  __syncthreads();
  if (flag[0] != SPLIT - 1) return;  // not last -> done
  __threadfence();                   // acquire: see all blocks' partials

  float* lsh = (float*)(Lds + 64);   // [128] row denominators
  if (tid < 128) {
    float l = 0.f;
#pragma unroll
    for (int ss = 0; ss < SPLIT; ++ss)
      l += Lpart[(size_t)ss * N_ + row0 + tid];
    lsh[tid] = 1.0f / l;
  }
  __syncthreads();

  const size_t base = (size_t)row0 * C_;
  for (int i = tid * 4; i < 128 * C_; i += 256 * 4) {   // 16 float4/thread
    float4 o = {0.f, 0.f, 0.f, 0.f};
#pragma unroll
    for (int ss = 0; ss < SPLIT; ++ss) {                // fixed order: deterministic
      const float4 p = *(const float4*)(Opart + (size_t)ss * N_ * C_ + base + i);
      o.x += p.x; o.y += p.y; o.z += p.z; o.w += p.w;
    }
    const float li = lsh[i >> 7];                       // all 4 cols same row
    float4 r; r.x = o.x * li; r.y = o.y * li; r.z = o.z * li; r.w = o.w * li;
    *(float4*)(out + base + i) = r;
  }
}

// fused prep: blk<N+M: row conversion + norms; else yT tiles; blk0 zeroes cnt
__global__ void prep_all(const float* __restrict__ x, const float* __restrict__ xn,
                         const float* __restrict__ y,
                         bf16* __restrict__ xb, bf16* __restrict__ xnb,
                         bf16* __restrict__ yT,
                         float* __restrict__ xsq, float* __restrict__ xnsq,
                         int* __restrict__ cnt)
{
  const int blk = blockIdx.x;
  const int t = threadIdx.x;
  if (blk == 0 && t < 32) cnt[t] = 0;          // fixup counters (re-zero each call)
  if (blk < N_ + M_) {
    const float* src; bf16* dst; float* sq; int row;
    if (blk < N_) { src = x;  dst = xb;  sq = xsq;  row = blk; }
    else          { src = xn; dst = xnb; sq = xnsq; row = blk - N_; }
    const float4 v = reinterpret_cast<const float4*>(src + (size_t)row * D_)[t];
    float ss = v.x * v.x + v.y * v.y + v.z * v.z + v.w * v.w;
    bf16x4 hv;
    hv[0] = (bf16)v.x; hv[1] = (bf16)v.y; hv[2] = (bf16)v.z; hv[3] = (bf16)v.w;
    *reinterpret_cast<bf16x4*>(dst + (size_t)row * D_ + t * 4) = hv;
#pragma unroll
    for (int o = 32; o > 0; o >>= 1) ss += __shfl_down(ss, o);
    __shared__ float red[4];
    if ((t & 63) == 0) red[t >> 6] = ss;
    __syncthreads();
    if (t == 0) sq[row] = red[0] + red[1] + red[2] + red[3];
  } else {
    // yT tile: y[8192][128] f32 -> yT[128][8192] bf16, 64 m-cols per block
    __shared__ bf16 tile[C_][72];
    const int m0 = (blk - (N_ + M_)) * 64;
#pragma unroll
    for (int i = 0; i < 32; ++i) {
      const int idx = i * 256 + t;               // 0..8191
      const int ml = idx >> 7, cc = idx & 127;
      tile[cc][ml] = (bf16)y[(size_t)(m0 + ml) * C_ + cc];
    }
    __syncthreads();
#pragma unroll
    for (int i = 0; i < 32; ++i) {
      const int idx = i * 256 + t;
      const int cc = idx >> 6, ml = idx & 63;
      yT[(size_t)cc * M_ + m0 + ml] = tile[cc][ml];
    }
  }
}

extern "C" void kernel_launch(void* const* d_in, const int* in_sizes, int n_in,
                              void* d_out, int out_size, void* d_ws, size_t ws_size,
                              hipStream_t stream)
{
  const float* x  = (const float*)d_in[0];
  const float* xn = (const float*)d_in[1];
  const float* y  = (const float*)d_in[2];
  // d_in[3] = log_T: computed-but-unused in the reference forward.
  float* out = (float*)d_out;

  char* ws = (char*)d_ws;
  bf16*  xb    = (bf16*)(ws);
  bf16*  xnb   = (bf16*)(ws + (size_t)8  * 1024 * 1024);
  bf16*  yT    = (bf16*)(ws + (size_t)24 * 1024 * 1024);
  float* xsq   = (float*)(ws + (size_t)26 * 1024 * 1024);
  float* xnsq  = (float*)(ws + (size_t)26 * 1024 * 1024 + 16 * 1024);
  float* Lpart = (float*)(ws + (size_t)26 * 1024 * 1024 + 64 * 1024);
  int*   cnt   = (int*)  (ws + (size_t)26 * 1024 * 1024 + 512 * 1024);
  float* Opart = (float*)(ws + (size_t)27 * 1024 * 1024);   // 16 x 2 MiB

  prep_all<<<N_ + M_ + M_ / 64, 256, 0, stream>>>(x, xn, y, xb, xnb, yT,
                                                  xsq, xnsq, cnt);
  nona_main<<<32 * SPLIT, 256, 0, stream>>>(xb, xnb, yT, xsq, xnsq,
                                            Opart, Lpart, cnt, out);
}

// Round 20
// 121.868 us; speedup vs baseline: 1.8621x; 1.8621x over previous
//
#include <hip/hip_runtime.h>

// NONA: out = softmax(-cdist(x, x_n), axis=1) @ y
//   x[4096,1024] f32, x_n[8192,1024] f32, y[8192,128] f32, log_T unused.
//
// R20 = FINAL: exact revert to R16/R18 (verified 4x: total 122.0us,
// main 95.5us, MfmaUtil 34%, absmax 0.0039).
//  * R19's in-kernel split-K fixup regressed 2x: per-block __threadfence()
//    (device-scope release) = L2 writeback/invalidate on non-coherent-L2
//    gfx950 -> 512 L2-flush storms + evicts co-resident block's panels.
//    Separate combine dispatch (~6us) is the correct design here.
//
// Final structure (equilibrium after 20 rounds of A/B):
//  * main: 128x128 tile, 4 waves x 64x64 quadrants (0.5 ds_read/MFMA,
//    Sacc[4][4] + Oacc[4][4]); LDS 64K = A-dbuf 2x16K + B-dbuf 2x16K,
//    seam aliases P[128][128]->A, V[128C][128]->B -> 2 blocks/CU.
//  * K-step: vmcnt(0); s_barrier; sched_barrier; {reads ks0 + stage(kk+1) +
//    MFMA ks0}; {reads ks1 + MFMA ks1}. Single barrier (R14 WAR proof:
//    reads(kk-1) consumed before bar1(kk) -> post-barrier restage safe).
//  * seam per bn: sync; stageV (flies under exp); exp; P-write; sync;
//    PV single pass; sync. XOR-granule swizzles (0 LDS read conflicts).
//  * 2D XCD chunking (xcd owns 16rb x 4s -> 4MB x + 4MB xn per L2);
//    SPLIT=16, grid 512 = exactly 2 blocks/CU.
//  * prep fused (rows + norms + yT transpose); combine reduces 16 partials.
//
// ws: xb@0 8Mi | xnb@8Mi 16Mi | yT@24Mi 2Mi | xsq@26Mi 16Ki | xnsq +16Ki |
//     Lpart@26Mi+64Ki 256Ki | Opart@27Mi 32Mi  (59Mi; ws>=93Mi proven R5)

#define N_ 4096
#define M_ 8192
#define D_ 1024
#define C_ 128
#define SPLIT 16
#define MCOLS (M_ / SPLIT)    // 512
#define NBN (MCOLS / 128)     // 4
#define NKK (D_ / 64)         // 16

typedef __bf16 bf16;
typedef __attribute__((ext_vector_type(8))) __bf16 bf16x8;
typedef __attribute__((ext_vector_type(4))) __bf16 bf16x4;
typedef __attribute__((ext_vector_type(4))) float f32x4;

__device__ __forceinline__ void async_copy16(const bf16* gp, void* lp) {
  __builtin_amdgcn_global_load_lds(
      (__attribute__((address_space(1))) void*)const_cast<bf16*>(gp),
      (__attribute__((address_space(3))) void*)lp, 16, 0, 0);
}

// 128-B-row tiles (A/B): 16B-granule XOR row&7 (0-conflict, R1-R18)
__device__ __forceinline__ int swz(int row, int gran) {
  return (row << 7) + ((gran ^ (row & 7)) << 4);
}
// 256-B-row tiles (P/V): 16 granules, XOR row&15
__device__ __forceinline__ int swz2(int row, int gran) {
  return (row << 8) + ((gran ^ (row & 15)) << 4);
}

// [128][64]-bf16 tile (16K, 16 chunks): 4 loads/thread @256 thr, src pre-swz
__device__ __forceinline__ void stage16(const bf16* src, char* lds, int tid) {
  const int lane = tid & 63, wave = tid >> 6;
#pragma unroll
  for (int j = 0; j < 4; ++j) {
    const int ch  = j * 4 + wave;
    const int off = ch * 1024 + lane * 16;
    const int row = off >> 7;
    const int gr  = ((off >> 4) & 7) ^ (row & 7);
    async_copy16(src + (size_t)row * D_ + gr * 8, lds + ch * 1024);
  }
}
// V = yT[128 C][128 xn] (32K, 256-B rows): 8 loads/thread @256 thr
__device__ __forceinline__ void stageV(const bf16* yT, int colbase, char* lds, int tid) {
  const int lane = tid & 63, wave = tid >> 6;
#pragma unroll
  for (int j = 0; j < 8; ++j) {
    const int ch  = j * 4 + wave;
    const int off = ch * 1024 + lane * 16;
    const int row = off >> 8;
    const int gr  = ((off >> 4) & 15) ^ (row & 15);
    async_copy16(yT + (size_t)row * M_ + colbase + gr * 8, lds + ch * 1024);
  }
}

#define VM0 asm volatile("s_waitcnt vmcnt(0)" ::: "memory")

__global__ __launch_bounds__(256, 2)   // 2 waves/EU => 2 blocks/CU
void nona_main(const bf16* __restrict__ xb, const bf16* __restrict__ xnb,
               const bf16* __restrict__ yT, const float* __restrict__ xsq,
               const float* __restrict__ xnsq, float* __restrict__ Opart,
               float* __restrict__ Lpart)
{
  __shared__ __align__(16) char Lds[65536];
  char* const A0 = Lds;             // x [128][64] even kk  | seam: P [128][128]
  char* const A1 = Lds + 16384;     // x [128][64] odd kk
  char* const B0 = Lds + 32768;     // xn [128][64] even kk | seam: V [128C][128]
  char* const B1 = Lds + 49152;     // xn [128][64] odd kk
  char* const Pb = A0;              // P, 256-B rows (swz2)
  char* const Vb = B0;              // V, 256-B rows (swz2)

  const int tid  = threadIdx.x;
  const int lane = tid & 63;
  const int wave = tid >> 6;           // 4 waves: wr = wave>>1 (64 rows), wc = wave&1
  const int wr = wave >> 1, wc = wave & 1;
  const int g = lane >> 4, c = lane & 15;

  // 2D XCD-chunked decode: xcd = bid&7 owns 16 rb x 4 s
  const int xcd = blockIdx.x & 7;
  const int idx = blockIdx.x >> 3;               // 0..63
  const int rb  = ((xcd >> 2) << 4) | (idx >> 2);   // 0..31
  const int s   = ((xcd & 3) << 2) | (idx & 3);     // 0..15
  const int row0 = rb * 128;
  const int col0 = s * MCOLS;

  const bf16* xA = xb + (size_t)row0 * D_;

  float xs[4];
#pragma unroll
  for (int rf = 0; rf < 4; ++rf)
    xs[rf] = xsq[row0 + wr * 64 + rf * 16 + c];

  f32x4 Oacc[4][4];
  const f32x4 zero = {0.f, 0.f, 0.f, 0.f};
#pragma unroll
  for (int rf = 0; rf < 4; ++rf)
#pragma unroll
    for (int cc = 0; cc < 4; ++cc) Oacc[rf][cc] = zero;
  float lsum[4] = {0.f, 0.f, 0.f, 0.f};

#pragma unroll 1
  for (int bn = 0; bn < NBN; ++bn) {
    const int colbase = col0 + bn * 128;
    const bf16* xB = xnb + (size_t)colbase * D_;

    f32x4 Sacc[4][4];
#pragma unroll
    for (int rf = 0; rf < 4; ++rf)
#pragma unroll
      for (int cf = 0; cf < 4; ++cf) Sacc[rf][cf] = zero;

    // prologue (prev bn sealed by post-PV syncthreads; vm=0): stage(0)
    stage16(xA, A0, tid);
    stage16(xB, B0, tid);

#pragma unroll 1
    for (int kk = 0; kk < NKK; ++kk) {
      VM0;                           // own stage(kk) landed (only outstanding
                                     // VMEM: stage(kk+1) not yet issued)
      __builtin_amdgcn_s_barrier();  // bar1: all waves' stage(kk) landed;
                                     // also: all waves consumed reads(kk-1)
                                     // before arriving -> WAR-safe restage
      __builtin_amdgcn_sched_barrier(0);
      const char* Ac = (kk & 1) ? A1 : A0;
      const char* Bc = (kk & 1) ? B1 : B0;
      // swapped-S: Sacc = mfma(A=xn_frag, B=x_frag) -> lane holds
      // S[xn = wc*64+cf*16+g*4+r][xrow = wr*64+rf*16+c]
      {
        bf16x8 af[4], bv[4];
#pragma unroll
        for (int rf = 0; rf < 4; ++rf)
          af[rf] = *(const bf16x8*)(Ac + swz(wr * 64 + rf * 16 + c, g));
#pragma unroll
        for (int j = 0; j < 4; ++j)
          bv[j] = *(const bf16x8*)(Bc + swz(wc * 64 + j * 16 + c, g));
        if (kk < NKK - 1) {          // stage(kk+1): AFTER bar1 -> WAR-safe
          stage16(xA + (kk + 1) * 64, (kk & 1) ? A0 : A1, tid);
          stage16(xB + (kk + 1) * 64, (kk & 1) ? B0 : B1, tid);
        }
        __builtin_amdgcn_s_setprio(1);
#pragma unroll
        for (int j = 0; j < 4; ++j)
#pragma unroll
          for (int rf = 0; rf < 4; ++rf)
            Sacc[rf][j] = __builtin_amdgcn_mfma_f32_16x16x32_bf16(
                bv[j], af[rf], Sacc[rf][j], 0, 0, 0);
        __builtin_amdgcn_s_setprio(0);
      }
      {
        bf16x8 af[4], bv[4];
#pragma unroll
        for (int rf = 0; rf < 4; ++rf)
          af[rf] = *(const bf16x8*)(Ac + swz(wr * 64 + rf * 16 + c, 4 + g));
#pragma unroll
        for (int j = 0; j < 4; ++j)
          bv[j] = *(const bf16x8*)(Bc + swz(wc * 64 + j * 16 + c, 4 + g));
        __builtin_amdgcn_s_setprio(1);
#pragma unroll
        for (int j = 0; j < 4; ++j)
#pragma unroll
          for (int rf = 0; rf < 4; ++rf)
            Sacc[rf][j] = __builtin_amdgcn_mfma_f32_16x16x32_bf16(
                bv[j], af[rf], Sacc[rf][j], 0, 0, 0);
        __builtin_amdgcn_s_setprio(0);
      }
      // no bar2: next step's bar1 provides the WAR seal (R14 proof)
    }
    __syncthreads();                 // seal kk15 readers; vm = 0 for alias reuse

    stageV(yT, colbase, Vb, tid);    // V -> B region (flies under exp)

    // exp: w = exp(-sqrt(max(xsq + xnsq - 2*dot, 0))); accumulate l
#pragma unroll
    for (int cf = 0; cf < 4; ++cf) {
      const float4 nsq4 = *(const float4*)(xnsq + colbase + wc * 64 + cf * 16 + g * 4);
#pragma unroll
      for (int rf = 0; rf < 4; ++rf)
#pragma unroll
        for (int r = 0; r < 4; ++r) {
          float d2 = xs[rf] + ((const float*)&nsq4)[r] - 2.0f * Sacc[rf][cf][r];
          d2 = fmaxf(d2, 0.0f);
          const float wv = __expf(-sqrtf(d2));
          lsum[rf] += wv;
          Sacc[rf][cf][r] = wv;
        }
    }

    // P-write -> A region [128 xrow][128 xn] swz2 (b64 per (rf,cf))
#pragma unroll
    for (int rf = 0; rf < 4; ++rf)
#pragma unroll
      for (int cf = 0; cf < 4; ++cf) {
        bf16x4 pk;
#pragma unroll
        for (int r = 0; r < 4; ++r) pk[r] = (bf16)Sacc[rf][cf][r];
        const int prow = wr * 64 + rf * 16 + c;
        const int gran = wc * 8 + cf * 2 + (g >> 1);
        *(bf16x4*)(Pb + (prow << 8) + ((gran ^ (prow & 15)) << 4) + (g & 1) * 8) = pk;
      }
    __syncthreads();                 // drains V (vmcnt0); P visible

    // PV: O[64 rows x 64 C-half] += P[64 x 128] @ V^T  (V [128C][128])
#pragma unroll
    for (int ks = 0; ks < 4; ++ks) {
      bf16x8 pa[4], vb[4];
#pragma unroll
      for (int rf = 0; rf < 4; ++rf)
        pa[rf] = *(const bf16x8*)(Pb + swz2(wr * 64 + rf * 16 + c, ks * 4 + g));
#pragma unroll
      for (int cc = 0; cc < 4; ++cc)
        vb[cc] = *(const bf16x8*)(Vb + swz2(wc * 64 + cc * 16 + c, ks * 4 + g));
      __builtin_amdgcn_s_setprio(1);
#pragma unroll
      for (int cc = 0; cc < 4; ++cc)
#pragma unroll
        for (int rf = 0; rf < 4; ++rf)
          Oacc[rf][cc] = __builtin_amdgcn_mfma_f32_16x16x32_bf16(pa[rf], vb[cc], Oacc[rf][cc], 0, 0, 0);
      __builtin_amdgcn_s_setprio(0);
    }
    __syncthreads();                 // seal P/V readers before next bn prologue
  }

  // ---- L reduce: over g (shfl), then the wc pair (LDS) ----
  float* Lr = (float*)Lds;           // [2 wc][128 rows]
#pragma unroll
  for (int rf = 0; rf < 4; ++rf) {
    float v = lsum[rf];
    v += __shfl_xor(v, 16);
    v += __shfl_xor(v, 32);
    if (g == 0) Lr[wc * 128 + wr * 64 + rf * 16 + c] = v;
  }
  __syncthreads();
  if (tid < 128)
    Lpart[(size_t)s * N_ + row0 + tid] = Lr[tid] + Lr[128 + tid];

  float* ob = Opart + ((size_t)s * N_ + row0) * C_;
#pragma unroll
  for (int rf = 0; rf < 4; ++rf)
#pragma unroll
    for (int cc = 0; cc < 4; ++cc)
#pragma unroll
      for (int r = 0; r < 4; ++r)
        ob[(wr * 64 + rf * 16 + g * 4 + r) * C_ + wc * 64 + cc * 16 + c] = Oacc[rf][cc][r];
}

// fused prep: blk<N+M: row conversion + norms; else: yT transpose tiles
__global__ void prep_all(const float* __restrict__ x, const float* __restrict__ xn,
                         const float* __restrict__ y,
                         bf16* __restrict__ xb, bf16* __restrict__ xnb,
                         bf16* __restrict__ yT,
                         float* __restrict__ xsq, float* __restrict__ xnsq)
{
  const int blk = blockIdx.x;
  const int t = threadIdx.x;
  if (blk < N_ + M_) {
    const float* src; bf16* dst; float* sq; int row;
    if (blk < N_) { src = x;  dst = xb;  sq = xsq;  row = blk; }
    else          { src = xn; dst = xnb; sq = xnsq; row = blk - N_; }
    const float4 v = reinterpret_cast<const float4*>(src + (size_t)row * D_)[t];
    float ss = v.x * v.x + v.y * v.y + v.z * v.z + v.w * v.w;
    bf16x4 hv;
    hv[0] = (bf16)v.x; hv[1] = (bf16)v.y; hv[2] = (bf16)v.z; hv[3] = (bf16)v.w;
    *reinterpret_cast<bf16x4*>(dst + (size_t)row * D_ + t * 4) = hv;
#pragma unroll
    for (int o = 32; o > 0; o >>= 1) ss += __shfl_down(ss, o);
    __shared__ float red[4];
    if ((t & 63) == 0) red[t >> 6] = ss;
    __syncthreads();
    if (t == 0) sq[row] = red[0] + red[1] + red[2] + red[3];
  } else {
    // yT tile: y[8192][128] f32 -> yT[128][8192] bf16, 64 m-cols per block
    __shared__ bf16 tile[C_][72];
    const int m0 = (blk - (N_ + M_)) * 64;
#pragma unroll
    for (int i = 0; i < 32; ++i) {
      const int idx = i * 256 + t;               // 0..8191
      const int ml = idx >> 7, cc = idx & 127;
      tile[cc][ml] = (bf16)y[(size_t)(m0 + ml) * C_ + cc];
    }
    __syncthreads();
#pragma unroll
    for (int i = 0; i < 32; ++i) {
      const int idx = i * 256 + t;
      const int cc = idx >> 6, ml = idx & 63;
      yT[(size_t)cc * M_ + m0 + ml] = tile[cc][ml];
    }
  }
}

__global__ void combine(const float* __restrict__ Opart, const float* __restrict__ Lpart,
                        float* __restrict__ out)
{
  const int i = blockIdx.x * 256 + threadIdx.x;   // < N_*C_
  const int row = i >> 7;
  float o = 0.f, l = 0.f;
#pragma unroll
  for (int s = 0; s < SPLIT; ++s) {
    o += Opart[(size_t)s * N_ * C_ + i];
    l += Lpart[(size_t)s * N_ + row];
  }
  out[i] = o / l;
}

extern "C" void kernel_launch(void* const* d_in, const int* in_sizes, int n_in,
                              void* d_out, int out_size, void* d_ws, size_t ws_size,
                              hipStream_t stream)
{
  const float* x  = (const float*)d_in[0];
  const float* xn = (const float*)d_in[1];
  const float* y  = (const float*)d_in[2];
  // d_in[3] = log_T: computed-but-unused in the reference forward.
  float* out = (float*)d_out;

  char* ws = (char*)d_ws;
  bf16*  xb    = (bf16*)(ws);
  bf16*  xnb   = (bf16*)(ws + (size_t)8  * 1024 * 1024);
  bf16*  yT    = (bf16*)(ws + (size_t)24 * 1024 * 1024);
  float* xsq   = (float*)(ws + (size_t)26 * 1024 * 1024);
  float* xnsq  = (float*)(ws + (size_t)26 * 1024 * 1024 + 16 * 1024);
  float* Lpart = (float*)(ws + (size_t)26 * 1024 * 1024 + 64 * 1024);
  float* Opart = (float*)(ws + (size_t)27 * 1024 * 1024);   // 16 x 2 MiB

  prep_all<<<N_ + M_ + M_ / 64, 256, 0, stream>>>(x, xn, y, xb, xnb, yT, xsq, xnsq);
  nona_main<<<32 * SPLIT, 256, 0, stream>>>(xb, xnb, yT, xsq, xnsq, Opart, Lpart);
  combine<<<(N_ * C_) / 256, 256, 0, stream>>>(Opart, Lpart, out);
}